// Round 5
// baseline (182.192 us; speedup 1.0000x reference)
//
#include <hip/hip_runtime.h>

// VQ-VAE eval forward, MFMA bf16x3-split path (fp32-faithful distances).
// B=64, D=64, H=32, W=32 -> N=65536 queries dim 64; K=1024 codes.
// dist(q,c) = ||e_c||^2 - 2 <x_q, e_c>  (||x||^2 dropped: per-query constant).
// <x,e> via 6 bf16 MFMA products: x=xh+xm+xl exactly; keep hh,hm,mh,mm,hl,lh.
//
// R5 = R0's EXACT fast structure (75us vq_main: 256-thr blocks, 512 blocks,
// 2 blocks/CU -> inter-block MFMA/staging overlap; stage_write at tile end =
// 96 MFMAs of load cover) + only the two independently-validated deltas:
//  - LDS write swizzle slot = code ^ (o<<1) (R4: conflicts 1.1e7 -> 7.9e5,
//    correctness held).
//  - fused last-block finalize (R1/R2/R4: correct; saves a launch).
// Lesson bank (R1-R4): MFMA cycles are invariant (~20us); every restructure
// that reduced co-resident independent blocks per CU (1-block/CU lockstep,
// or per-wave serial load chains) added 40-50us of pure stall. Keep 2/CU.

#define DIMS 64
#define K_CODES 1024
#define N_QUERIES 65536
#define HW 1024
#define TOTAL_ELEMS 4194304
#define PLANE 4096   // shorts per plane in a code-tile buffer
#define NBLK 512

typedef __attribute__((ext_vector_type(8))) short v8s;   // 8 bf16 = 4 VGPR (A/B frag)
typedef __attribute__((ext_vector_type(4))) float f32x4; // C/D frag

__device__ inline unsigned short f2bf(float x) {
    union { float f; unsigned u; } v; v.f = x;
    unsigned r = v.u + 0x7fff + ((v.u >> 16) & 1);  // RNE
    return (unsigned short)(r >> 16);
}
__device__ inline float bf2f(unsigned short h) {
    union { unsigned u; float f; } v; v.u = ((unsigned)h) << 16; return v.f;
}

// ---------------- Kernel A: code norms + zero accumulators ----------------
__global__ void vq_prep(const float* __restrict__ emb, float* __restrict__ ws_norm,
                        unsigned* __restrict__ ws_flags, float* __restrict__ ws_loss,
                        int* __restrict__ ws_cnt) {
    int k = blockIdx.x * 256 + threadIdx.x;  // 0..1023
    const float4* row = (const float4*)(emb + k * DIMS);
    float s = 0.f;
#pragma unroll
    for (int i = 0; i < 16; ++i) {
        float4 v = row[i];
        s += v.x * v.x + v.y * v.y + v.z * v.z + v.w * v.w;
    }
    ws_norm[k] = s;
    if (k < 32) ws_flags[k] = 0u;
    if (k == 0) { *ws_loss = 0.f; *ws_cnt = 0; }
}

#define MFMA16(A_, B_, C_) __builtin_amdgcn_mfma_f32_16x16x32_bf16(A_, B_, C_, 0, 0, 0)

// ---------------- Kernel B: MFMA distances + argmin + gather + loss + finalize ------
// 512 blocks x 256 threads (4 waves), 2 blocks/CU. Block = 128 queries;
// wave = 32 queries (2 row-tiles of 16), each wave scans ALL 1024 codes
// in 16 tiles of 64.
__global__ __launch_bounds__(256, 2)
void vq_main(const float* __restrict__ z_e, const float* __restrict__ emb,
             const float* __restrict__ ws_norm, unsigned* __restrict__ ws_flags,
             float* __restrict__ ws_loss, int* __restrict__ ws_cnt,
             float* __restrict__ out) {
    // Double-buffered code tile, frag-ready: [buf][plane p][octet o][slot][8 bf16]
    // slot = code ^ (o<<1)  (bank-conflict swizzle on code bits 1-3)
    __shared__ unsigned short ldsB[2][3 * PLANE];  // 48 KB
    __shared__ int      fIdx[128];
    __shared__ float    wsum[4];
    __shared__ unsigned umask[32];
    __shared__ int      lastBlk;

    const int tid  = threadIdx.x;
    const int lane = tid & 63;
    const int wid  = tid >> 6;
    const int qbase = blockIdx.x * 128;
    const int b    = qbase >> 10;          // batch index (uniform per block)
    const int hwb  = qbase & (HW - 1);

    const int col  = lane & 15;  // m (A) / n (B) within 16-tile
    const int qd   = lane >> 4;  // quad -> k-octet selector

    if (tid < 32) umask[tid] = 0u;

    // ---- Build A fragments from global (coalesced), split into 3 bf16 planes ----
    v8s afr[2][2][3];
    {
        const float* zb = z_e + b * (DIMS * HW);
#pragma unroll
        for (int rt = 0; rt < 2; ++rt) {
            int hwq = hwb + wid * 32 + rt * 16 + col;
#pragma unroll
            for (int kc = 0; kc < 2; ++kc) {
                int dbase = kc * 32 + qd * 8;
#pragma unroll
                for (int j = 0; j < 8; ++j) {
                    float x = zb[(dbase + j) * HW + hwq];
                    unsigned short h = f2bf(x);  float r1 = x - bf2f(h);
                    unsigned short m = f2bf(r1); float r2 = r1 - bf2f(m);
                    afr[rt][kc][0][j] = (short)h;
                    afr[rt][kc][1][j] = (short)m;
                    afr[rt][kc][2][j] = (short)f2bf(r2);
                }
            }
        }
    }

    float bestv[2][4];
    int   besti[2][4];
#pragma unroll
    for (int rt = 0; rt < 2; ++rt)
#pragma unroll
        for (int r = 0; r < 4; ++r) { bestv[rt][r] = 3.4e38f; besti[rt][r] = 0; }

    float4 regs[4];  // staging pipeline registers (16 fp32 = one 64-code tile / 256 thr)

    // Stage tile t's 64x64 fp32 into regs (fully coalesced: tile is contiguous).
    auto stage_loads = [&](int t) {
        const float4* src = (const float4*)(emb + t * 64 * DIMS);
#pragma unroll
        for (int i = 0; i < 4; ++i) regs[i] = src[tid + 256 * i];
    };
    // Split + scatter into frag-ready LDS layout, swizzled (8B ds_writes).
    auto stage_write = [&](int bb) {
        unsigned short* dst = &ldsB[bb][0];
#pragma unroll
        for (int i = 0; i < 4; ++i) {
            int e    = (tid + 256 * i) * 4;  // flat element in tile
            int code = e >> 6;
            int d    = e & 63;               // 4-aligned
            int o    = d >> 3;
            int sub  = d & 7;                // 0 or 4
            float xs[4] = {regs[i].x, regs[i].y, regs[i].z, regs[i].w};
            unsigned short h[4], mm_[4], l[4];
#pragma unroll
            for (int q = 0; q < 4; ++q) {
                float x = xs[q];
                unsigned short hh = f2bf(x);  float r1 = x - bf2f(hh);
                unsigned short mh = f2bf(r1); float r2 = r1 - bf2f(mh);
                h[q] = hh; mm_[q] = mh; l[q] = f2bf(r2);
            }
            int base = (o * 64 + (code ^ (o << 1))) * 8 + sub;  // swizzled slot
            uint2 uh, um, ul;
            uh.x = (unsigned)h[0]   | ((unsigned)h[1] << 16);
            uh.y = (unsigned)h[2]   | ((unsigned)h[3] << 16);
            um.x = (unsigned)mm_[0] | ((unsigned)mm_[1] << 16);
            um.y = (unsigned)mm_[2] | ((unsigned)mm_[3] << 16);
            ul.x = (unsigned)l[0]   | ((unsigned)l[1] << 16);
            ul.y = (unsigned)l[2]   | ((unsigned)l[3] << 16);
            *(uint2*)(dst + base)             = uh;
            *(uint2*)(dst + PLANE + base)     = um;
            *(uint2*)(dst + 2 * PLANE + base) = ul;
        }
    };

    stage_loads(0);
    stage_write(0);
    __syncthreads();

    for (int t = 0; t < 16; ++t) {
        const int cur = t & 1;
        if (t < 15) stage_loads(t + 1);
        const unsigned short* bufc = &ldsB[cur][0];
#pragma unroll
        for (int cs = 0; cs < 4; ++cs) {
            float nrm = ws_norm[t * 64 + cs * 16 + col];
            // B-frags: B[n=col][k=qd*8+j], octet = kc*4+qd, swizzled slot.
            v8s bfr[2][3];
#pragma unroll
            for (int kc = 0; kc < 2; ++kc) {
                int oct = kc * 4 + qd;
                int slot = (cs * 16 + col) ^ (oct << 1);
#pragma unroll
                for (int p = 0; p < 3; ++p)
                    bfr[kc][p] = *(const v8s*)(bufc + p * PLANE + (oct * 64 + slot) * 8);
            }
            f32x4 acc0 = {0.f, 0.f, 0.f, 0.f};
            f32x4 acc1 = {0.f, 0.f, 0.f, 0.f};
#pragma unroll
            for (int kc = 0; kc < 2; ++kc) {
                acc0 = MFMA16(afr[0][kc][0], bfr[kc][0], acc0);  // hh
                acc1 = MFMA16(afr[1][kc][0], bfr[kc][0], acc1);
                acc0 = MFMA16(afr[0][kc][0], bfr[kc][1], acc0);  // hm
                acc1 = MFMA16(afr[1][kc][0], bfr[kc][1], acc1);
                acc0 = MFMA16(afr[0][kc][1], bfr[kc][0], acc0);  // mh
                acc1 = MFMA16(afr[1][kc][1], bfr[kc][0], acc1);
                acc0 = MFMA16(afr[0][kc][1], bfr[kc][1], acc0);  // mm
                acc1 = MFMA16(afr[1][kc][1], bfr[kc][1], acc1);
                acc0 = MFMA16(afr[0][kc][0], bfr[kc][2], acc0);  // hl
                acc1 = MFMA16(afr[1][kc][0], bfr[kc][2], acc1);
                acc0 = MFMA16(afr[0][kc][2], bfr[kc][0], acc0);  // lh
                acc1 = MFMA16(afr[1][kc][2], bfr[kc][0], acc1);
            }
            int cbase = t * 64 + cs * 16 + col;
#pragma unroll
            for (int r = 0; r < 4; ++r) {
                float d0 = fmaf(-2.f, acc0[r], nrm);
                if (d0 < bestv[0][r]) { bestv[0][r] = d0; besti[0][r] = cbase; }
                float d1 = fmaf(-2.f, acc1[r], nrm);
                if (d1 < bestv[1][r]) { bestv[1][r] = d1; besti[1][r] = cbase; }
            }
        }
        if (t < 15) stage_write(1 - cur);  // other buffer: safe while peers finish cur
        __syncthreads();
    }

    // ---- Final argmin across the 16 columns held by this quad's lanes ----
#pragma unroll
    for (int rt = 0; rt < 2; ++rt)
#pragma unroll
    for (int r = 0; r < 4; ++r) {
        float v = bestv[rt][r];
        int   idx = besti[rt][r];
#pragma unroll
        for (int m = 8; m >= 1; m >>= 1) {
            float ov = __shfl_xor(v, m, 64);
            int   oi = __shfl_xor(idx, m, 64);
            if (ov < v || (ov == v && oi < idx)) { v = ov; idx = oi; }
        }
        if (col == 0) {
            int q = wid * 32 + rt * 16 + qd * 4 + r;  // within block
            fIdx[q] = idx;
            out[TOTAL_ELEMS + 1 + qbase + q] = (float)idx;
            atomicOr(&umask[idx >> 5], 1u << (idx & 31));  // LDS, cheap
        }
    }
    __syncthreads();

    // ---- Gather z_q, write coalesced, accumulate mse partial ----
    const int q  = tid & 127;
    const int dh = tid >> 7;  // even/odd dims
    const int n  = qbase + q;
    const int bb = n >> 10;
    const int hw = n & (HW - 1);
    const int myIdx = fIdx[q];
    const float* erow = emb + myIdx * DIMS;
    float lsum = 0.f;
#pragma unroll
    for (int it = 0; it < 32; ++it) {
        int d = it * 2 + dh;
        float v = erow[d];                         // random row, L2/L3-resident
        int   o = bb * (DIMS * HW) + d * HW + hw;  // consecutive q -> coalesced
        float ze = z_e[o];
        out[o] = v;
        float df = ze - v;
        lsum = fmaf(df, df, lsum);
    }
#pragma unroll
    for (int off = 32; off > 0; off >>= 1) lsum += __shfl_down(lsum, off, 64);
    if (lane == 0) wsum[wid] = lsum;
    __syncthreads();

    // ---- Publish block results (device-scope) + last-block finalize ----
    if (tid < 32) atomicOr(&ws_flags[tid], umask[tid]);
    if (tid == 0) atomicAdd(ws_loss, wsum[0] + wsum[1] + wsum[2] + wsum[3]);
    __threadfence();  // drain this block's atomics before taking the ticket
    if (tid == 0) lastBlk = (atomicAdd(ws_cnt, 1) == NBLK - 1) ? 1 : 0;
    __syncthreads();
    if (lastBlk) {
        int c = 0;
        if (tid < 32) c = __popc(atomicOr(&ws_flags[tid], 0u));  // coherent read
        if (tid < 64) {
#pragma unroll
            for (int off = 32; off >= 1; off >>= 1) c += __shfl_down(c, off, 64);
        }
        if (tid == 0) {
            float L = atomicAdd(ws_loss, 0.f);  // coherent read
            out[TOTAL_ELEMS] = L / (float)TOTAL_ELEMS;
            out[TOTAL_ELEMS + 1 + N_QUERIES] = (float)c / (float)K_CODES;
        }
    }
}

extern "C" void kernel_launch(void* const* d_in, const int* in_sizes, int n_in,
                              void* d_out, int out_size, void* d_ws, size_t ws_size,
                              hipStream_t stream) {
    const float* z_e = (const float*)d_in[0];
    const float* emb = (const float*)d_in[1];
    float* out = (float*)d_out;
    float*    ws_norm  = (float*)d_ws;
    unsigned* ws_flags = (unsigned*)((char*)d_ws + 4096);
    float*    ws_loss  = (float*)((char*)d_ws + 8192);
    int*      ws_cnt   = (int*)((char*)d_ws + 8256);

    vq_prep<<<4, 256, 0, stream>>>(emb, ws_norm, ws_flags, ws_loss, ws_cnt);
    vq_main<<<NBLK, 256, 0, stream>>>(z_e, emb, ws_norm, ws_flags, ws_loss,
                                      ws_cnt, out);
}

// Round 6
// 136.544 us; speedup vs baseline: 1.3343x; 1.3343x over previous
//
#include <hip/hip_runtime.h>

// VQ-VAE eval forward, MFMA bf16x3-split path (fp32-faithful distances).
// B=64, D=64, H=32, W=32 -> N=65536 queries dim 64; K=1024 codes.
// dist(q,c) = ||e_c||^2 - 2 <x_q, e_c>  (||x||^2 dropped: per-query constant,
// fp32 add of a constant is monotonic -> argmin preserved incl. tie order).
// <x,e> via 6 bf16 MFMA products: x=xh+xm+xl exactly (8+8+8 bits), keep
// hh,hm,mh,mm,hl,lh -> error ~2^-27*scale, below fp32 reorder noise.
//
// R6 = R0 (75us vq_main) + ONLY the LDS write swizzle. Separate vq_final
// kernel RESTORED. A/B evidence across R1/R2/R4/R5: four different main-loop
// structures, all with the fused last-block finalize (__threadfence + ticket
// + device atomics), all ~117-128us with identical MFMA/VALU busy-time to
// R0 (~20.5/25.8us) -> the fused finalize costs ~45us of structure-
// independent idle (agent-scope fence => L2 writeback x512 blocks, plus
// contended device atomics). The swizzle is independently validated
// (conflicts 1.1e7 -> 1.6e6, correctness held in R4/R5).

#define DIMS 64
#define K_CODES 1024
#define N_QUERIES 65536
#define HW 1024
#define TOTAL_ELEMS 4194304
#define PLANE 4096  // shorts per plane in a code-tile buffer: 8 octets * 64 codes * 8

typedef __attribute__((ext_vector_type(8))) short v8s;   // 8 bf16 = 4 VGPR (A/B frag)
typedef __attribute__((ext_vector_type(4))) float f32x4; // C/D frag

__device__ inline unsigned short f2bf(float x) {
    union { float f; unsigned u; } v; v.f = x;
    unsigned r = v.u + 0x7fff + ((v.u >> 16) & 1);  // RNE
    return (unsigned short)(r >> 16);
}
__device__ inline float bf2f(unsigned short h) {
    union { unsigned u; float f; } v; v.u = ((unsigned)h) << 16; return v.f;
}

// ---------------- Kernel A: code norms + zero accumulators ----------------
__global__ void vq_prep(const float* __restrict__ emb, float* __restrict__ ws_norm,
                        int* __restrict__ ws_flags, float* __restrict__ ws_loss) {
    int k = blockIdx.x * 256 + threadIdx.x;  // 0..1023
    const float4* row = (const float4*)(emb + k * DIMS);
    float s = 0.f;
#pragma unroll
    for (int i = 0; i < 16; ++i) {
        float4 v = row[i];
        s += v.x * v.x + v.y * v.y + v.z * v.z + v.w * v.w;
    }
    ws_norm[k] = s;
    ws_flags[k] = 0;
    if (k == 0) *ws_loss = 0.f;
}

#define MFMA16(A_, B_, C_) __builtin_amdgcn_mfma_f32_16x16x32_bf16(A_, B_, C_, 0, 0, 0)

// ---------------- Kernel B: MFMA distances + argmin + gather + loss ----------------
// 512 blocks x 256 threads (4 waves), 2 blocks/CU. Block = 128 queries; wave =
// 32 queries (2 row-tiles of 16), each wave scans ALL 1024 codes in 16 tiles of 64.
__global__ __launch_bounds__(256, 2)
void vq_main(const float* __restrict__ z_e, const float* __restrict__ emb,
             const float* __restrict__ ws_norm, int* __restrict__ ws_flags,
             float* __restrict__ ws_loss, float* __restrict__ out) {
    // Double-buffered code tile, frag-ready: [buf][plane p][octet o][slot][8 bf16]
    // slot = code ^ (o<<1)  (bank-conflict swizzle on code bits 1-3)
    __shared__ unsigned short ldsB[2][3 * PLANE];  // 48 KB
    __shared__ int   fIdx[128];
    __shared__ float wsum[4];

    const int tid  = threadIdx.x;
    const int lane = tid & 63;
    const int wid  = tid >> 6;
    const int qbase = blockIdx.x * 128;
    const int b    = qbase >> 10;          // batch index (uniform per block)
    const int hwb  = qbase & (HW - 1);

    const int col  = lane & 15;  // m (A) / n (B) within 16-tile
    const int qd   = lane >> 4;  // quad -> k-octet selector

    // ---- Build A fragments from global (coalesced), split into 3 bf16 planes ----
    // A[m=col][k=qd*8+j]; dims d = kc*32 + qd*8 + j. afr[rt][kc][plane]
    v8s afr[2][2][3];
    {
        const float* zb = z_e + b * (DIMS * HW);
#pragma unroll
        for (int rt = 0; rt < 2; ++rt) {
            int hwq = hwb + wid * 32 + rt * 16 + col;
#pragma unroll
            for (int kc = 0; kc < 2; ++kc) {
                int dbase = kc * 32 + qd * 8;
#pragma unroll
                for (int j = 0; j < 8; ++j) {
                    float x = zb[(dbase + j) * HW + hwq];
                    unsigned short h = f2bf(x);  float r1 = x - bf2f(h);
                    unsigned short m = f2bf(r1); float r2 = r1 - bf2f(m);
                    afr[rt][kc][0][j] = (short)h;
                    afr[rt][kc][1][j] = (short)m;
                    afr[rt][kc][2][j] = (short)f2bf(r2);
                }
            }
        }
    }

    float bestv[2][4];
    int   besti[2][4];
#pragma unroll
    for (int rt = 0; rt < 2; ++rt)
#pragma unroll
        for (int r = 0; r < 4; ++r) { bestv[rt][r] = 3.4e38f; besti[rt][r] = 0; }

    float4 regs[4];  // staging pipeline registers (16 fp32 = one 64-code tile / 256 thr)

    // Stage tile t's 64x64 fp32 into regs (fully coalesced: tile is contiguous).
    auto stage_loads = [&](int t) {
        const float4* src = (const float4*)(emb + t * 64 * DIMS);
#pragma unroll
        for (int i = 0; i < 4; ++i) regs[i] = src[tid + 256 * i];
    };
    // Split + scatter into frag-ready LDS layout, swizzled (8B ds_writes).
    auto stage_write = [&](int bb) {
        unsigned short* dst = &ldsB[bb][0];
#pragma unroll
        for (int i = 0; i < 4; ++i) {
            int e    = (tid + 256 * i) * 4;  // flat element in tile
            int code = e >> 6;
            int d    = e & 63;               // 4-aligned
            int o    = d >> 3;
            int sub  = d & 7;                // 0 or 4
            float xs[4] = {regs[i].x, regs[i].y, regs[i].z, regs[i].w};
            unsigned short h[4], mm_[4], l[4];
#pragma unroll
            for (int q = 0; q < 4; ++q) {
                float x = xs[q];
                unsigned short hh = f2bf(x);  float r1 = x - bf2f(hh);
                unsigned short mh = f2bf(r1); float r2 = r1 - bf2f(mh);
                h[q] = hh; mm_[q] = mh; l[q] = f2bf(r2);
            }
            int base = (o * 64 + (code ^ (o << 1))) * 8 + sub;  // swizzled slot
            uint2 uh, um, ul;
            uh.x = (unsigned)h[0]   | ((unsigned)h[1] << 16);
            uh.y = (unsigned)h[2]   | ((unsigned)h[3] << 16);
            um.x = (unsigned)mm_[0] | ((unsigned)mm_[1] << 16);
            um.y = (unsigned)mm_[2] | ((unsigned)mm_[3] << 16);
            ul.x = (unsigned)l[0]   | ((unsigned)l[1] << 16);
            ul.y = (unsigned)l[2]   | ((unsigned)l[3] << 16);
            *(uint2*)(dst + base)             = uh;
            *(uint2*)(dst + PLANE + base)     = um;
            *(uint2*)(dst + 2 * PLANE + base) = ul;
        }
    };

    stage_loads(0);
    stage_write(0);
    __syncthreads();

    for (int t = 0; t < 16; ++t) {
        const int cur = t & 1;
        if (t < 15) stage_loads(t + 1);
        const unsigned short* bufc = &ldsB[cur][0];
#pragma unroll
        for (int cs = 0; cs < 4; ++cs) {
            float nrm = ws_norm[t * 64 + cs * 16 + col];
            // B-frags: B[n=col][k=qd*8+j], octet = kc*4+qd, swizzled slot.
            v8s bfr[2][3];
#pragma unroll
            for (int kc = 0; kc < 2; ++kc) {
                int oct  = kc * 4 + qd;
                int slot = (cs * 16 + col) ^ (oct << 1);
#pragma unroll
                for (int p = 0; p < 3; ++p)
                    bfr[kc][p] = *(const v8s*)(bufc + p * PLANE + (oct * 64 + slot) * 8);
            }
            f32x4 acc0 = {0.f, 0.f, 0.f, 0.f};
            f32x4 acc1 = {0.f, 0.f, 0.f, 0.f};
#pragma unroll
            for (int kc = 0; kc < 2; ++kc) {
                acc0 = MFMA16(afr[0][kc][0], bfr[kc][0], acc0);  // hh
                acc1 = MFMA16(afr[1][kc][0], bfr[kc][0], acc1);
                acc0 = MFMA16(afr[0][kc][0], bfr[kc][1], acc0);  // hm
                acc1 = MFMA16(afr[1][kc][0], bfr[kc][1], acc1);
                acc0 = MFMA16(afr[0][kc][1], bfr[kc][0], acc0);  // mh
                acc1 = MFMA16(afr[1][kc][1], bfr[kc][0], acc1);
                acc0 = MFMA16(afr[0][kc][1], bfr[kc][1], acc0);  // mm
                acc1 = MFMA16(afr[1][kc][1], bfr[kc][1], acc1);
                acc0 = MFMA16(afr[0][kc][0], bfr[kc][2], acc0);  // hl
                acc1 = MFMA16(afr[1][kc][0], bfr[kc][2], acc1);
                acc0 = MFMA16(afr[0][kc][2], bfr[kc][0], acc0);  // lh
                acc1 = MFMA16(afr[1][kc][2], bfr[kc][0], acc1);
            }
            int cbase = t * 64 + cs * 16 + col;
#pragma unroll
            for (int r = 0; r < 4; ++r) {
                float d0 = fmaf(-2.f, acc0[r], nrm);
                if (d0 < bestv[0][r]) { bestv[0][r] = d0; besti[0][r] = cbase; }
                float d1 = fmaf(-2.f, acc1[r], nrm);
                if (d1 < bestv[1][r]) { bestv[1][r] = d1; besti[1][r] = cbase; }
            }
        }
        if (t < 15) stage_write(1 - cur);  // other buffer: safe while peers finish cur
        __syncthreads();
    }

    // ---- Final argmin across the 16 columns held by this quad's lanes ----
    // C/D: row = qd*4 + r, col = lane&15. Lanes of a quad share rows, span cols.
#pragma unroll
    for (int rt = 0; rt < 2; ++rt)
#pragma unroll
    for (int r = 0; r < 4; ++r) {
        float v = bestv[rt][r];
        int   idx = besti[rt][r];
#pragma unroll
        for (int m = 8; m >= 1; m >>= 1) {
            float ov = __shfl_xor(v, m, 64);
            int   oi = __shfl_xor(idx, m, 64);
            if (ov < v || (ov == v && oi < idx)) { v = ov; idx = oi; }
        }
        if (col == 0) {
            int q = wid * 32 + rt * 16 + qd * 4 + r;  // within block
            fIdx[q] = idx;
            out[TOTAL_ELEMS + 1 + qbase + q] = (float)idx;
            ws_flags[idx] = 1;  // benign race
        }
    }
    __syncthreads();

    // ---- Gather z_q, write coalesced, accumulate mse partial ----
    const int q  = tid & 127;
    const int dh = tid >> 7;  // even/odd dims
    const int n  = qbase + q;
    const int bb = n >> 10;
    const int hw = n & (HW - 1);
    const int myIdx = fIdx[q];
    const float* erow = emb + myIdx * DIMS;
    float lsum = 0.f;
#pragma unroll
    for (int it = 0; it < 32; ++it) {
        int d = it * 2 + dh;
        float v = erow[d];                         // random row, L2/L3-resident
        int   o = bb * (DIMS * HW) + d * HW + hw;  // consecutive q -> coalesced
        float ze = z_e[o];
        out[o] = v;
        float df = ze - v;
        lsum = fmaf(df, df, lsum);
    }
#pragma unroll
    for (int off = 32; off > 0; off >>= 1) lsum += __shfl_down(lsum, off, 64);
    if (lane == 0) wsum[wid] = lsum;
    __syncthreads();
    if (tid == 0) atomicAdd(ws_loss, wsum[0] + wsum[1] + wsum[2] + wsum[3]);
}

// ---------------- Kernel C: finalize loss + usage ----------------
__global__ void vq_final(const int* __restrict__ flags, const float* __restrict__ loss,
                         float* __restrict__ out) {
    __shared__ int cnt[256];
    int tid = threadIdx.x;
    int c = flags[tid] + flags[tid + 256] + flags[tid + 512] + flags[tid + 768];
    cnt[tid] = c;
    __syncthreads();
    for (int s = 128; s > 0; s >>= 1) {
        if (tid < s) cnt[tid] += cnt[tid + s];
        __syncthreads();
    }
    if (tid == 0) {
        out[TOTAL_ELEMS] = *loss / (float)TOTAL_ELEMS;
        out[TOTAL_ELEMS + 1 + N_QUERIES] = (float)cnt[0] / (float)K_CODES;
    }
}

extern "C" void kernel_launch(void* const* d_in, const int* in_sizes, int n_in,
                              void* d_out, int out_size, void* d_ws, size_t ws_size,
                              hipStream_t stream) {
    const float* z_e = (const float*)d_in[0];
    const float* emb = (const float*)d_in[1];
    float* out = (float*)d_out;
    float* ws_norm  = (float*)d_ws;
    int*   ws_flags = (int*)((char*)d_ws + 4096);
    float* ws_loss  = (float*)((char*)d_ws + 8192);

    vq_prep<<<4, 256, 0, stream>>>(emb, ws_norm, ws_flags, ws_loss);
    vq_main<<<512, 256, 0, stream>>>(z_e, emb, ws_norm, ws_flags, ws_loss, out);
    vq_final<<<1, 256, 0, stream>>>(ws_flags, ws_loss, out);
}